// Round 6
// baseline (964.558 us; speedup 1.0000x reference)
//
#include <hip/hip_runtime.h>
#include <math.h>

#define GRID_N 512
#define IM_N   256
#define NCOIL  8
#define NK     131072
#define PLANE  (GRID_N*GRID_N)
#define JW     6
#define NENT   (NK*JW)
#define BETA_F 13.8551003f   /* pi*sqrt((6/2)^2*(2-0.5)^2 - 0.8) */
#define KSCALE 81.48733086305042f  /* 512/(2*pi) */

struct cplx { float x, y; };

__device__ __forceinline__ float bessel_i0f(float x){
  // Abramowitz & Stegun 9.8.1 / 9.8.2, rel err < 2e-7
  if (x < 3.75f){
    float t = x*(1.0f/3.75f); t = t*t;
    return 1.0f + t*(3.5156229f + t*(3.0899424f + t*(1.2067492f
           + t*(0.2659732f + t*(0.0360768f + t*0.0045813f)))));
  } else {
    float t = 3.75f/x;
    float p = 0.39894228f + t*(0.01328592f + t*(0.00225319f + t*(-0.00157565f
            + t*(0.00916281f + t*(-0.02057706f + t*(0.02635537f
            + t*(-0.01647633f + t*0.00392377f)))))));
    return p * __expf(x) * rsqrtf(x);
  }
}

__device__ __forceinline__ float kb_w(float u){   // 1-axis KB weight, |u|<=3
  float uu = u*(1.0f/3.0f);
  float q = fmaxf(1.0f - uu*uu, 0.0f);
  return bessel_i0f(BETA_F*sqrtf(q)) * (1.0f/6.0f);
}

__device__ __forceinline__ unsigned bf16_of(float f){
  unsigned u = __float_as_uint(f);
  return (u + 0x8000u) >> 16;                 // round-to-nearest-ish
}

// Kaiser-Bessel apodization correction row table sc[256]
__global__ void k_sc_table(float* sc){
  int i = threadIdx.x;
  if (i >= IM_N) return;
  float n  = (i - IM_N*0.5f) * (1.0f/GRID_N);
  float pj = 3.14159265358979f * (float)JW * n;
  float t  = BETA_F*BETA_F - pj*pj;
  float sp = sqrtf(fmaxf(t, 1e-12f));
  float sn = sqrtf(fmaxf(-t, 1e-12f));
  float ft = (t > 0.0f) ? (sinhf(sp)/sp) : (sinf(sn)/sn);
  float sc0 = sinhf(BETA_F)/BETA_F;
  sc[i] = sc0/ft;
}

__global__ void k_zero4(float4* p, int n4){
  int i = blockIdx.x*blockDim.x + threadIdx.x;
  if (i < n4) p[i] = make_float4(0.f,0.f,0.f,0.f);
}

__global__ void k_zero1(float* p, int n){
  int i = blockIdx.x*blockDim.x + threadIdx.x;
  if (i < n) p[i] = 0.f;
}

// coil_images * sc2 into padded 512^2 planar grids (A zeroed beforehand)
__global__ void k_fill(const float* __restrict__ ximg, const float* __restrict__ sr,
                       const float* __restrict__ si, const float* __restrict__ sc,
                       cplx* __restrict__ A){
  int idx = blockIdx.x*blockDim.x + threadIdx.x;   // c*65536 + y*256 + x
  if (idx >= NCOIL*IM_N*IM_N) return;
  int c = idx >> 16;
  int pix = idx & 65535;
  int y = pix >> 8, x = pix & 255;
  float v = ximg[pix] * sc[y]*sc[x];
  cplx o; o.x = v * sr[idx]; o.y = v * si[idx];
  A[(size_t)c*PLANE + y*GRID_N + x] = o;
}

// in-place 512-pt radix-2 FFT on each contiguous row; DIR=-1 fwd, +1 inv(unnorm)
template<int DIR>
__global__ void k_fft_rows(cplx* __restrict__ buf, float scale){
  __shared__ cplx lds[GRID_N];
  cplx* p = buf + (size_t)blockIdx.x * GRID_N;
  int tid = threadIdx.x;                       // 256 threads
  for (int i = tid; i < GRID_N; i += 256){
    int r = __brev((unsigned)i) >> 23;         // 9-bit reverse
    lds[r] = p[i];
  }
  __syncthreads();
  for (int half = 1; half < GRID_N; half <<= 1){
    int j = tid & (half-1);
    int k = ((tid & ~(half-1)) << 1) | j;
    float ang = (float)DIR * 3.14159265358979f * (float)j / (float)half;
    float sw, cw; __sincosf(ang, &sw, &cw);
    cplx u = lds[k];
    cplx v = lds[k+half];
    cplx t; t.x = v.x*cw - v.y*sw; t.y = v.x*sw + v.y*cw;
    lds[k].x      = u.x + t.x; lds[k].y      = u.y + t.y;
    lds[k+half].x = u.x - t.x; lds[k+half].y = u.y - t.y;
    __syncthreads();
  }
  for (int i = tid; i < GRID_N; i += 256){
    cplx v = lds[i]; v.x *= scale; v.y *= scale; p[i] = v;
  }
}

// 512x512 tile transpose per coil plane, out[X][Y] = in[Y][X]
__global__ void k_transpose(const cplx* __restrict__ in, cplx* __restrict__ out){
  __shared__ cplx tile[32][33];
  int c  = blockIdx.z;
  int x0 = blockIdx.x*32, y0 = blockIdx.y*32;
  const cplx* ip = in  + (size_t)c*PLANE;
  cplx*       op = out + (size_t)c*PLANE;
  int tx = threadIdx.x, ty = threadIdx.y;      // (32,8)
  for (int dy = 0; dy < 32; dy += 8)
    tile[ty+dy][tx] = ip[(size_t)(y0+ty+dy)*GRID_N + (x0+tx)];
  __syncthreads();
  for (int dy = 0; dy < 32; dy += 8)
    op[(size_t)(x0+ty+dy)*GRID_N + (y0+tx)] = tile[tx][ty+dy];
}

// planar [c][cell] -> coil-interleaved [cell][8 float2]  (fully coalesced)
__global__ void k_c2i(const float2* __restrict__ plan, float2* __restrict__ inter){
  int t = blockIdx.x*blockDim.x + threadIdx.x;
  if (t >= PLANE*NCOIL) return;
  int c = t & 7; int cell = t >> 3;
  inter[(size_t)cell*8 + c] = plan[(size_t)c*PLANE + cell];
}

// coil-interleaved [cell][8 float2] -> planar [c][cell]
__global__ void k_i2c(const float2* __restrict__ inter, float2* __restrict__ plan){
  int t = blockIdx.x*blockDim.x + threadIdx.x;
  if (t >= PLANE*NCOIL) return;
  int c = t & 7; int cell = t >> 3;
  plan[(size_t)c*PLANE + cell] = inter[(size_t)cell*8 + c];
}

// forward interp + lambda blend: thread = (sample, coil-pair)
__global__ __launch_bounds__(256) void k_fwd(
    const float* __restrict__ ktraj, const float* __restrict__ yre,
    const float* __restrict__ yim, const float* __restrict__ lraw,
    const float4* __restrict__ KTi4, float4* __restrict__ kdc4){
  int t = blockIdx.x*blockDim.x + threadIdx.x;
  if (t >= NK*4) return;
  int k = t >> 2, p = t & 3;

  int iy[JW], ix[JW]; float wy[JW], wx[JW];
  {
    float tm = ktraj[k] * KSCALE;
    int base = (int)floorf(tm - 3.0f);
    #pragma unroll
    for (int j = 1; j <= JW; ++j){
      int fidx = base + j;
      wy[j-1] = kb_w(tm - (float)fidx);
      iy[j-1] = fidx & (GRID_N-1);
    }
  }
  {
    float tm = ktraj[NK + k] * KSCALE;
    int base = (int)floorf(tm - 3.0f);
    #pragma unroll
    for (int j = 1; j <= JW; ++j){
      int fidx = base + j;
      wx[j-1] = kb_w(tm - (float)fidx);
      ix[j-1] = fidx & (GRID_N-1);
    }
  }

  float ax=0.f, ay=0.f, az=0.f, aw=0.f;
  #pragma unroll
  for (int jx = 0; jx < JW; ++jx){
    int ox = ix[jx]*GRID_N;
    #pragma unroll
    for (int jy = 0; jy < JW; ++jy){
      float w2 = wx[jx]*wy[jy];
      float4 v = KTi4[(size_t)(ox + iy[jy])*4 + p];
      ax += w2*v.x; ay += w2*v.y; az += w2*v.z; aw += w2*v.w;
    }
  }
  float lam = 1.0f/(1.0f + __expf(-lraw[0]));
  float oml = 1.0f - lam;
  int c0 = 2*p;
  float4 o;
  o.x = lam*ax + oml*yre[(size_t)c0*NK + k];
  o.y = lam*ay + oml*yim[(size_t)c0*NK + k];
  o.z = lam*az + oml*yre[(size_t)(c0+1)*NK + k];
  o.w = lam*aw + oml*yim[(size_t)(c0+1)*NK + k];
  kdc4[(size_t)k*4 + p] = o;
}

// histogram over x-base bins + per-sample rank
__global__ void k_hist(const float* __restrict__ ktraj, unsigned* __restrict__ hist,
                       unsigned* __restrict__ rank){
  int k = blockIdx.x*blockDim.x + threadIdx.x;
  if (k >= NK) return;
  float tmx = ktraj[NK + k] * KSCALE;
  int bx = (int)floorf(tmx - 3.0f);
  rank[k] = atomicAdd(&hist[bx & (GRID_N-1)], 1u);
}

// column counts + exclusive scan (single block of 512)
__global__ void k_scan512(const unsigned* __restrict__ hist, unsigned* __restrict__ colOff){
  __shared__ unsigned s[GRID_N];
  int t = threadIdx.x;
  unsigned v = 0;
  #pragma unroll
  for (int d = 1; d <= JW; ++d) v += hist[(t - d) & (GRID_N-1)];
  s[t] = v;
  __syncthreads();
  for (int off = 1; off < GRID_N; off <<= 1){
    unsigned add = (t >= off) ? s[t - off] : 0u;
    __syncthreads();
    s[t] += add;
    __syncthreads();
  }
  colOff[t] = (t == 0) ? 0u : s[t-1];
}

// place fully-expanded 16B records at closed-form positions (no contention):
// rec = { bf16(wx*wy0)|bf16(wx*wy1)<<16, bf16(wx*wy2)|bf16(wx*wy3)<<16,
//         bf16(wx*wy4)|bf16(wx*wy5)<<16, (kk<<9)|(by&511) }
__global__ void k_fill_entries(const float* __restrict__ ktraj,
                               const unsigned* __restrict__ rank,
                               const unsigned* __restrict__ hist,
                               const unsigned* __restrict__ colOff,
                               uint4* __restrict__ entries){
  int k = blockIdx.x*blockDim.x + threadIdx.x;
  if (k >= NK) return;
  float tmy = ktraj[k] * KSCALE;
  int by = (int)floorf(tmy - 3.0f);
  float wy[JW];
  #pragma unroll
  for (int j = 1; j <= JW; ++j) wy[j-1] = kb_w(tmy - (float)(by + j));

  float tmx = ktraj[NK + k] * KSCALE;
  int bx = (int)floorf(tmx - 3.0f);
  unsigned r = rank[k];
  unsigned tag = ((unsigned)k << 9) | ((unsigned)(by & (GRID_N-1)));
  unsigned run = 0;
  #pragma unroll
  for (int j = 1; j <= JW; ++j){
    int cc = (bx + j) & (GRID_N-1);
    float wx = kb_w(tmx - (float)(bx + j));
    uint4 rec;
    rec.x = bf16_of(wx*wy[0]) | (bf16_of(wx*wy[1]) << 16);
    rec.y = bf16_of(wx*wy[2]) | (bf16_of(wx*wy[3]) << 16);
    rec.z = bf16_of(wx*wy[4]) | (bf16_of(wx*wy[5]) << 16);
    rec.w = tag;
    entries[colOff[cc] + run + r] = rec;
    run += hist[cc];
  }
}

// adjoint gridding scan: block = (x-column, q-half). Lane = (entry-sub 0..7,
// q-sub 0..7). Streams 16B records; kdc lines read fully-coalesced 32B per
// entry; 6 ds_add per lane into a 16KB LDS tile acc[y][8]. No indirection.
__global__ __launch_bounds__(256) void k_scan_col(
    const uint4* __restrict__ entries, const unsigned* __restrict__ colOff,
    const float* __restrict__ kdcf,     // [k][16] floats
    float4* __restrict__ HTi4){         // [cell][4 float4]
  __shared__ float acc[GRID_N*8];
  const int c = blockIdx.x, h = blockIdx.y;    // column, q-half
  const int tid = threadIdx.x;
  const int ql = tid & 7;                      // q within half
  const int es = tid >> 3;                     // entry-sub 0..31
  for (int i = tid; i < GRID_N*8; i += 256) acc[i] = 0.f;
  __syncthreads();

  unsigned beg = colOff[c];
  unsigned end = (c < GRID_N-1) ? colOff[c+1] : (unsigned)NENT;

  for (unsigned base = beg; base < end; base += 32){
    unsigned e = base + es;
    if (e < end){
      uint4 rec = entries[e];
      unsigned kk = rec.w >> 9;
      int by = (int)(rec.w & (GRID_N-1));
      float v = kdcf[(size_t)kk*16 + h*8 + ql];
      float w0 = __uint_as_float(rec.x << 16);
      float w1 = __uint_as_float(rec.x & 0xFFFF0000u);
      float w2 = __uint_as_float(rec.y << 16);
      float w3 = __uint_as_float(rec.y & 0xFFFF0000u);
      float w4 = __uint_as_float(rec.z << 16);
      float w5 = __uint_as_float(rec.z & 0xFFFF0000u);
      int y;
      y = (by+1)&(GRID_N-1); atomicAdd(&acc[y*8+ql], w0*v);
      y = (by+2)&(GRID_N-1); atomicAdd(&acc[y*8+ql], w1*v);
      y = (by+3)&(GRID_N-1); atomicAdd(&acc[y*8+ql], w2*v);
      y = (by+4)&(GRID_N-1); atomicAdd(&acc[y*8+ql], w3*v);
      y = (by+5)&(GRID_N-1); atomicAdd(&acc[y*8+ql], w4*v);
      y = (by+6)&(GRID_N-1); atomicAdd(&acc[y*8+ql], w5*v);
    }
  }
  __syncthreads();

  // disjoint writeback: this block owns float4 slots p = h*2+{0,1} of each cell
  for (int i = tid; i < GRID_N*2; i += 256){
    int y = i >> 1, pp = i & 1;
    float4 o;
    o.x = acc[y*8 + pp*4 + 0];
    o.y = acc[y*8 + pp*4 + 1];
    o.z = acc[y*8 + pp*4 + 2];
    o.w = acc[y*8 + pp*4 + 3];
    HTi4[((size_t)c*GRID_N + y)*4 + h*2 + pp] = o;
  }
}

// crop, apodize, conj(smaps) coil-combine; ACCUMULATES into out
__global__ void k_final(const cplx* __restrict__ Bg, const float* __restrict__ sr,
                        const float* __restrict__ si, const float* __restrict__ sc,
                        float* __restrict__ out, int pairs){
  int idx = blockIdx.x*blockDim.x + threadIdx.x;   // y*256+x
  if (idx >= IM_N*IM_N) return;
  int y = idx >> 8, x = idx & 255;
  float s2 = sc[y]*sc[x];
  float ax = 0.f, ay = 0.f;
  #pragma unroll
  for (int c = 0; c < NCOIL; ++c){
    cplx v = Bg[(size_t)c*PLANE + y*GRID_N + x];
    int gi = (c << 16) | idx;
    float rr = sr[gi], ii = si[gi];
    ax += rr*v.x + ii*v.y;      // conj(s)*v real
    ay += rr*v.y - ii*v.x;      // conj(s)*v imag
  }
  if (pairs){
    out[idx*2]   += ax * s2;
    out[idx*2+1] += ay * s2;
  } else {
    out[idx]     += ax * s2;
  }
}

// ---------------- fallback (round-2 validated fused atomic path) -------------
__global__ void k_gather_scatter_fb(const float* __restrict__ ktraj,
                                    const float* __restrict__ yre,
                                    const float* __restrict__ yim,
                                    const float* __restrict__ lraw,
                                    const cplx* __restrict__ KT,
                                    float* __restrict__ HT){
  int k = blockIdx.x*blockDim.x + threadIdx.x;
  if (k >= NK) return;
  float lam   = 1.0f/(1.0f + __expf(-lraw[0]));
  float omlam = 1.0f - lam;
  int iy[JW], ix[JW]; float wy[JW], wx[JW];
  {
    float tm = ktraj[k] * KSCALE;
    int base = (int)floorf(tm - 3.0f);
    #pragma unroll
    for (int j = 1; j <= JW; ++j){
      wy[j-1] = kb_w(tm - (float)(base+j));
      iy[j-1] = (base+j) & (GRID_N-1);
    }
  }
  {
    float tm = ktraj[NK + k] * KSCALE;
    int base = (int)floorf(tm - 3.0f);
    #pragma unroll
    for (int j = 1; j <= JW; ++j){
      wx[j-1] = kb_w(tm - (float)(base+j));
      ix[j-1] = (base+j) & (GRID_N-1);
    }
  }
  float accx[NCOIL], accy[NCOIL];
  #pragma unroll
  for (int c = 0; c < NCOIL; ++c){ accx[c]=0.f; accy[c]=0.f; }
  #pragma unroll
  for (int jx = 0; jx < JW; ++jx){
    int ox = ix[jx]*GRID_N;
    #pragma unroll
    for (int jy = 0; jy < JW; ++jy){
      float w2 = wx[jx]*wy[jy];
      size_t o = (size_t)(ox + iy[jy]);
      #pragma unroll
      for (int c = 0; c < NCOIL; ++c){
        cplx v = KT[(size_t)c*PLANE + o];
        accx[c] += w2*v.x; accy[c] += w2*v.y;
      }
    }
  }
  float kdx[NCOIL], kdy[NCOIL];
  #pragma unroll
  for (int c = 0; c < NCOIL; ++c){
    kdx[c] = lam*accx[c] + omlam*yre[(size_t)c*NK + k];
    kdy[c] = lam*accy[c] + omlam*yim[(size_t)c*NK + k];
  }
  #pragma unroll
  for (int jx = 0; jx < JW; ++jx){
    int ox = ix[jx]*GRID_N;
    #pragma unroll
    for (int jy = 0; jy < JW; ++jy){
      float w2 = wx[jx]*wy[jy];
      size_t o = (size_t)(ox + iy[jy]);
      #pragma unroll
      for (int c = 0; c < NCOIL; ++c){
        float* dst = HT + ((size_t)c*PLANE + o)*2;
        atomicAdd(dst,   w2*kdx[c]);
        atomicAdd(dst+1, w2*kdy[c]);
      }
    }
  }
}

extern "C" void kernel_launch(void* const* d_in, const int* in_sizes, int n_in,
                              void* d_out, int out_size, void* d_ws, size_t ws_size,
                              hipStream_t stream) {
  const float* ximg  = (const float*)d_in[0];
  const float* yre   = (const float*)d_in[1];
  const float* yim   = (const float*)d_in[2];
  const float* sre   = (const float*)d_in[3];
  const float* sim   = (const float*)d_in[4];
  const float* ktraj = (const float*)d_in[5];
  const float* lraw  = (const float*)d_in[6];
  float* out = (float*)d_out;

  char* ws = (char*)d_ws;
  const size_t REG = 16777216;                 // one planar grid: 512*512*8B*8
  int pairs = (out_size >= 2*IM_N*IM_N) ? 1 : 0;

  // primary layout (50.34 MB):
  //   [0, REG)      A planar; after fwd: kdc (8MB) + rank (0.5MB); later img planar
  //   [REG, 2REG)   B planar (KT); after c2i+fwd: fat entries (12.6MB); later img^T
  //   [2REG, 3REG)  KTi interleaved; reused as HTi by k_scan_col
  //   [3REG, ...)   sc (4KB), hist (2KB), colOff (2KB)
  const size_t need = 3*REG + 4096 + 2048 + 2048;

  if (ws_size >= need){
    cplx*     A     = (cplx*)ws;
    cplx*     Bb    = (cplx*)(ws + REG);
    float4*   KTi4  = (float4*)(ws + 2*REG);
    float*    sc    = (float*)(ws + 3*REG);
    unsigned* hist  = (unsigned*)(ws + 3*REG + 4096);
    unsigned* colOff= (unsigned*)(ws + 3*REG + 4096 + 2048);
    float4*   kdc4  = (float4*)ws;                         // overlays dead A
    unsigned* rank  = (unsigned*)(ws + (size_t)NK*16*4);   // +8,388,608
    uint4*    entries = (uint4*)(ws + REG);                // overlays dead Bb

    const int n4 = NCOIL*PLANE*2/4;

    k_sc_table<<<1,256,0,stream>>>(sc);
    k_zero4<<<(n4+255)/256,256,0,stream>>>((float4*)A, n4);
    k_fill<<<(NCOIL*IM_N*IM_N+255)/256,256,0,stream>>>(ximg, sre, sim, sc, A);

    // fwd fft2/512: rows over x, transpose, rows over y -> Bb = kg^T planar [x][y]
    k_fft_rows<-1><<<NCOIL*GRID_N,256,0,stream>>>(A, 1.0f);
    k_transpose<<<dim3(16,16,NCOIL),dim3(32,8),0,stream>>>(A, Bb);
    k_fft_rows<-1><<<NCOIL*GRID_N,256,0,stream>>>(Bb, 1.0f/(float)GRID_N);

    k_c2i<<<(PLANE*NCOIL+255)/256,256,0,stream>>>((const float2*)Bb, (float2*)KTi4);

    // forward interp + blend -> kdc over dead A (Bb planar now dead)
    k_fwd<<<(NK*4+255)/256,256,0,stream>>>(ktraj, yre, yim, lraw, KTi4, kdc4);

    // column binning (131K int atomics total)
    k_zero1<<<2,256,0,stream>>>((float*)hist, GRID_N);
    k_hist<<<NK/256,256,0,stream>>>(ktraj, hist, rank);
    k_scan512<<<1,GRID_N,0,stream>>>(hist, colOff);
    k_fill_entries<<<NK/256,256,0,stream>>>(ktraj, rank, hist, colOff, entries);

    // adjoint gridding: 512 columns x 2 q-halves, streaming fat records,
    // 16KB LDS tiles, disjoint writeback over dead KTi
    k_scan_col<<<dim3(GRID_N,2),256,0,stream>>>(entries, colOff,
                                                (const float*)kdc4,
                                                KTi4);

    k_i2c<<<(PLANE*NCOIL+255)/256,256,0,stream>>>((const float2*)KTi4, (float2*)A);

    // adjoint ifft2*512: rows over y, transpose, rows over x -> Bb = img [y][x]
    k_fft_rows<+1><<<NCOIL*GRID_N,256,0,stream>>>(A, 1.0f);
    k_transpose<<<dim3(16,16,NCOIL),dim3(32,8),0,stream>>>(A, Bb);
    k_fft_rows<+1><<<NCOIL*GRID_N,256,0,stream>>>(Bb, 1.0f/(float)GRID_N);

    k_zero1<<<(out_size+255)/256,256,0,stream>>>(out, out_size);
    k_final<<<(IM_N*IM_N+255)/256,256,0,stream>>>(Bb, sre, sim, sc, out, pairs);
  } else {
    // fallback: round-2 validated path (needs 33.6 MB)
    float* sc = (float*)ws;
    cplx*  A  = (cplx*)(ws + 4096);
    cplx*  Bb = (cplx*)(ws + 4096 + REG);
    const int n4 = NCOIL*PLANE*2/4;

    k_sc_table<<<1,256,0,stream>>>(sc);
    k_zero4<<<(n4+255)/256,256,0,stream>>>((float4*)A, n4);
    k_fill<<<(NCOIL*IM_N*IM_N+255)/256,256,0,stream>>>(ximg, sre, sim, sc, A);
    k_fft_rows<-1><<<NCOIL*GRID_N,256,0,stream>>>(A, 1.0f);
    k_transpose<<<dim3(16,16,NCOIL),dim3(32,8),0,stream>>>(A, Bb);
    k_fft_rows<-1><<<NCOIL*GRID_N,256,0,stream>>>(Bb, 1.0f/(float)GRID_N);
    k_zero4<<<(n4+255)/256,256,0,stream>>>((float4*)A, n4);
    k_gather_scatter_fb<<<(NK+255)/256,256,0,stream>>>(ktraj, yre, yim, lraw, Bb, (float*)A);
    k_fft_rows<+1><<<NCOIL*GRID_N,256,0,stream>>>(A, 1.0f);
    k_transpose<<<dim3(16,16,NCOIL),dim3(32,8),0,stream>>>(A, Bb);
    k_fft_rows<+1><<<NCOIL*GRID_N,256,0,stream>>>(Bb, 1.0f/(float)GRID_N);
    k_zero1<<<(out_size+255)/256,256,0,stream>>>(out, out_size);
    k_final<<<(IM_N*IM_N+255)/256,256,0,stream>>>(Bb, sre, sim, sc, out, pairs);
  }
}

// Round 7
// 961.346 us; speedup vs baseline: 1.0033x; 1.0033x over previous
//
#include <hip/hip_runtime.h>
#include <math.h>

#define GRID_N 512
#define IM_N   256
#define NCOIL  8
#define NK     131072
#define PLANE  (GRID_N*GRID_N)
#define JW     6
#define NENT   (NK*JW)
#define BETA_F 13.8551003f   /* pi*sqrt((6/2)^2*(2-0.5)^2 - 0.8) */
#define KSCALE 81.48733086305042f  /* 512/(2*pi) */

struct cplx { float x, y; };

__device__ __forceinline__ float bessel_i0f(float x){
  // Abramowitz & Stegun 9.8.1 / 9.8.2, rel err < 2e-7
  if (x < 3.75f){
    float t = x*(1.0f/3.75f); t = t*t;
    return 1.0f + t*(3.5156229f + t*(3.0899424f + t*(1.2067492f
           + t*(0.2659732f + t*(0.0360768f + t*0.0045813f)))));
  } else {
    float t = 3.75f/x;
    float p = 0.39894228f + t*(0.01328592f + t*(0.00225319f + t*(-0.00157565f
            + t*(0.00916281f + t*(-0.02057706f + t*(0.02635537f
            + t*(-0.01647633f + t*0.00392377f)))))));
    return p * __expf(x) * rsqrtf(x);
  }
}

__device__ __forceinline__ float kb_w(float u){   // 1-axis KB weight, |u|<=3
  float uu = u*(1.0f/3.0f);
  float q = fmaxf(1.0f - uu*uu, 0.0f);
  return bessel_i0f(BETA_F*sqrtf(q)) * (1.0f/6.0f);
}

__device__ __forceinline__ unsigned bf16_of(float f){
  unsigned u = __float_as_uint(f);
  return (u + 0x8000u) >> 16;                 // round-to-nearest-ish
}

// Kaiser-Bessel apodization correction row table sc[256]
__global__ void k_sc_table(float* sc){
  int i = threadIdx.x;
  if (i >= IM_N) return;
  float n  = (i - IM_N*0.5f) * (1.0f/GRID_N);
  float pj = 3.14159265358979f * (float)JW * n;
  float t  = BETA_F*BETA_F - pj*pj;
  float sp = sqrtf(fmaxf(t, 1e-12f));
  float sn = sqrtf(fmaxf(-t, 1e-12f));
  float ft = (t > 0.0f) ? (sinhf(sp)/sp) : (sinf(sn)/sn);
  float sc0 = sinhf(BETA_F)/BETA_F;
  sc[i] = sc0/ft;
}

__global__ void k_zero4(float4* p, int n4){
  int i = blockIdx.x*blockDim.x + threadIdx.x;
  if (i < n4) p[i] = make_float4(0.f,0.f,0.f,0.f);
}

__global__ void k_zero1(float* p, int n){
  int i = blockIdx.x*blockDim.x + threadIdx.x;
  if (i < n) p[i] = 0.f;
}

// coil_images * sc2 into padded 512^2 planar grids (A zeroed beforehand)
__global__ void k_fill(const float* __restrict__ ximg, const float* __restrict__ sr,
                       const float* __restrict__ si, const float* __restrict__ sc,
                       cplx* __restrict__ A){
  int idx = blockIdx.x*blockDim.x + threadIdx.x;   // c*65536 + y*256 + x
  if (idx >= NCOIL*IM_N*IM_N) return;
  int c = idx >> 16;
  int pix = idx & 65535;
  int y = pix >> 8, x = pix & 255;
  float v = ximg[pix] * sc[y]*sc[x];
  cplx o; o.x = v * sr[idx]; o.y = v * si[idx];
  A[(size_t)c*PLANE + y*GRID_N + x] = o;
}

// in-place 512-pt radix-2 FFT on each contiguous row; DIR=-1 fwd, +1 inv(unnorm)
template<int DIR>
__global__ void k_fft_rows(cplx* __restrict__ buf, float scale){
  __shared__ cplx lds[GRID_N];
  cplx* p = buf + (size_t)blockIdx.x * GRID_N;
  int tid = threadIdx.x;                       // 256 threads
  for (int i = tid; i < GRID_N; i += 256){
    int r = __brev((unsigned)i) >> 23;         // 9-bit reverse
    lds[r] = p[i];
  }
  __syncthreads();
  for (int half = 1; half < GRID_N; half <<= 1){
    int j = tid & (half-1);
    int k = ((tid & ~(half-1)) << 1) | j;
    float ang = (float)DIR * 3.14159265358979f * (float)j / (float)half;
    float sw, cw; __sincosf(ang, &sw, &cw);
    cplx u = lds[k];
    cplx v = lds[k+half];
    cplx t; t.x = v.x*cw - v.y*sw; t.y = v.x*sw + v.y*cw;
    lds[k].x      = u.x + t.x; lds[k].y      = u.y + t.y;
    lds[k+half].x = u.x - t.x; lds[k+half].y = u.y - t.y;
    __syncthreads();
  }
  for (int i = tid; i < GRID_N; i += 256){
    cplx v = lds[i]; v.x *= scale; v.y *= scale; p[i] = v;
  }
}

// 512x512 tile transpose per coil plane, out[X][Y] = in[Y][X]
__global__ void k_transpose(const cplx* __restrict__ in, cplx* __restrict__ out){
  __shared__ cplx tile[32][33];
  int c  = blockIdx.z;
  int x0 = blockIdx.x*32, y0 = blockIdx.y*32;
  const cplx* ip = in  + (size_t)c*PLANE;
  cplx*       op = out + (size_t)c*PLANE;
  int tx = threadIdx.x, ty = threadIdx.y;      // (32,8)
  for (int dy = 0; dy < 32; dy += 8)
    tile[ty+dy][tx] = ip[(size_t)(y0+ty+dy)*GRID_N + (x0+tx)];
  __syncthreads();
  for (int dy = 0; dy < 32; dy += 8)
    op[(size_t)(x0+ty+dy)*GRID_N + (y0+tx)] = tile[tx][ty+dy];
}

// planar [c][cell] -> coil-interleaved [cell][8 float2]  (fully coalesced)
__global__ void k_c2i(const float2* __restrict__ plan, float2* __restrict__ inter){
  int t = blockIdx.x*blockDim.x + threadIdx.x;
  if (t >= PLANE*NCOIL) return;
  int c = t & 7; int cell = t >> 3;
  inter[(size_t)cell*8 + c] = plan[(size_t)c*PLANE + cell];
}

// coil-interleaved [cell][8 float2] -> planar [c][cell]
__global__ void k_i2c(const float2* __restrict__ inter, float2* __restrict__ plan){
  int t = blockIdx.x*blockDim.x + threadIdx.x;
  if (t >= PLANE*NCOIL) return;
  int c = t & 7; int cell = t >> 3;
  plan[(size_t)c*PLANE + cell] = inter[(size_t)cell*8 + c];
}

// forward interp + lambda blend: thread = (sample, coil-pair)
__global__ __launch_bounds__(256) void k_fwd(
    const float* __restrict__ ktraj, const float* __restrict__ yre,
    const float* __restrict__ yim, const float* __restrict__ lraw,
    const float4* __restrict__ KTi4, float4* __restrict__ kdc4){
  int t = blockIdx.x*blockDim.x + threadIdx.x;
  if (t >= NK*4) return;
  int k = t >> 2, p = t & 3;

  int iy[JW], ix[JW]; float wy[JW], wx[JW];
  {
    float tm = ktraj[k] * KSCALE;
    int base = (int)floorf(tm - 3.0f);
    #pragma unroll
    for (int j = 1; j <= JW; ++j){
      int fidx = base + j;
      wy[j-1] = kb_w(tm - (float)fidx);
      iy[j-1] = fidx & (GRID_N-1);
    }
  }
  {
    float tm = ktraj[NK + k] * KSCALE;
    int base = (int)floorf(tm - 3.0f);
    #pragma unroll
    for (int j = 1; j <= JW; ++j){
      int fidx = base + j;
      wx[j-1] = kb_w(tm - (float)fidx);
      ix[j-1] = fidx & (GRID_N-1);
    }
  }

  float ax=0.f, ay=0.f, az=0.f, aw=0.f;
  #pragma unroll
  for (int jx = 0; jx < JW; ++jx){
    int ox = ix[jx]*GRID_N;
    #pragma unroll
    for (int jy = 0; jy < JW; ++jy){
      float w2 = wx[jx]*wy[jy];
      float4 v = KTi4[(size_t)(ox + iy[jy])*4 + p];
      ax += w2*v.x; ay += w2*v.y; az += w2*v.z; aw += w2*v.w;
    }
  }
  float lam = 1.0f/(1.0f + __expf(-lraw[0]));
  float oml = 1.0f - lam;
  int c0 = 2*p;
  float4 o;
  o.x = lam*ax + oml*yre[(size_t)c0*NK + k];
  o.y = lam*ay + oml*yim[(size_t)c0*NK + k];
  o.z = lam*az + oml*yre[(size_t)(c0+1)*NK + k];
  o.w = lam*aw + oml*yim[(size_t)(c0+1)*NK + k];
  kdc4[(size_t)k*4 + p] = o;
}

// histogram over x-base bins + per-sample rank
__global__ void k_hist(const float* __restrict__ ktraj, unsigned* __restrict__ hist,
                       unsigned* __restrict__ rank){
  int k = blockIdx.x*blockDim.x + threadIdx.x;
  if (k >= NK) return;
  float tmx = ktraj[NK + k] * KSCALE;
  int bx = (int)floorf(tmx - 3.0f);
  rank[k] = atomicAdd(&hist[bx & (GRID_N-1)], 1u);
}

// column counts + exclusive scan (single block of 512)
__global__ void k_scan512(const unsigned* __restrict__ hist, unsigned* __restrict__ colOff){
  __shared__ unsigned s[GRID_N];
  int t = threadIdx.x;
  unsigned v = 0;
  #pragma unroll
  for (int d = 1; d <= JW; ++d) v += hist[(t - d) & (GRID_N-1)];
  s[t] = v;
  __syncthreads();
  for (int off = 1; off < GRID_N; off <<= 1){
    unsigned add = (t >= off) ? s[t - off] : 0u;
    __syncthreads();
    s[t] += add;
    __syncthreads();
  }
  colOff[t] = (t == 0) ? 0u : s[t-1];
}

// place fully-expanded 16B records at closed-form positions (no contention):
// rec = { bf16(wx*wy0)|bf16(wx*wy1)<<16, bf16(wx*wy2)|bf16(wx*wy3)<<16,
//         bf16(wx*wy4)|bf16(wx*wy5)<<16, (kk<<9)|(by&511) }
__global__ void k_fill_entries(const float* __restrict__ ktraj,
                               const unsigned* __restrict__ rank,
                               const unsigned* __restrict__ hist,
                               const unsigned* __restrict__ colOff,
                               uint4* __restrict__ entries){
  int k = blockIdx.x*blockDim.x + threadIdx.x;
  if (k >= NK) return;
  float tmy = ktraj[k] * KSCALE;
  int by = (int)floorf(tmy - 3.0f);
  float wy[JW];
  #pragma unroll
  for (int j = 1; j <= JW; ++j) wy[j-1] = kb_w(tmy - (float)(by + j));

  float tmx = ktraj[NK + k] * KSCALE;
  int bx = (int)floorf(tmx - 3.0f);
  unsigned r = rank[k];
  unsigned tag = ((unsigned)k << 9) | ((unsigned)(by & (GRID_N-1)));
  unsigned run = 0;
  #pragma unroll
  for (int j = 1; j <= JW; ++j){
    int cc = (bx + j) & (GRID_N-1);
    float wx = kb_w(tmx - (float)(bx + j));
    uint4 rec;
    rec.x = bf16_of(wx*wy[0]) | (bf16_of(wx*wy[1]) << 16);
    rec.y = bf16_of(wx*wy[2]) | (bf16_of(wx*wy[3]) << 16);
    rec.z = bf16_of(wx*wy[4]) | (bf16_of(wx*wy[5]) << 16);
    rec.w = tag;
    entries[colOff[cc] + run + r] = rec;
    run += hist[cc];
  }
}

// one entry's contribution for one coil-float q: 6 LDS atomics
__device__ __forceinline__ void scan_apply(uint4 rec, float v, int ql, float* acc){
  int by = (int)(rec.w & (GRID_N-1));
  float w0 = __uint_as_float(rec.x << 16);
  float w1 = __uint_as_float(rec.x & 0xFFFF0000u);
  float w2 = __uint_as_float(rec.y << 16);
  float w3 = __uint_as_float(rec.y & 0xFFFF0000u);
  float w4 = __uint_as_float(rec.z << 16);
  float w5 = __uint_as_float(rec.z & 0xFFFF0000u);
  int y;
  y = (by+1)&(GRID_N-1); atomicAdd(&acc[y*8+ql], w0*v);
  y = (by+2)&(GRID_N-1); atomicAdd(&acc[y*8+ql], w1*v);
  y = (by+3)&(GRID_N-1); atomicAdd(&acc[y*8+ql], w2*v);
  y = (by+4)&(GRID_N-1); atomicAdd(&acc[y*8+ql], w3*v);
  y = (by+5)&(GRID_N-1); atomicAdd(&acc[y*8+ql], w4*v);
  y = (by+6)&(GRID_N-1); atomicAdd(&acc[y*8+ql], w5*v);
}

// adjoint gridding scan: block = (x-column, q-half), 512 threads (8 waves).
// Lane = (entry-sub es 0..63, q-sub ql 0..7). U=8 batching: 8 independent
// record loads then 8 independent kdc loads per iteration (MLP=8), then
// 48 ds_adds into a 16KB LDS tile acc[y][8]. Named regs (no dyn indexing).
__global__ __launch_bounds__(512) void k_scan_col(
    const uint4* __restrict__ entries, const unsigned* __restrict__ colOff,
    const float* __restrict__ kdcf,     // [k][16] floats
    float4* __restrict__ HTi4){         // [cell][4 float4]
  __shared__ float acc[GRID_N*8];
  const int c = blockIdx.x, h = blockIdx.y;    // column, q-half
  const int tid = threadIdx.x;
  const int ql = tid & 7;                      // q within half
  const int es = tid >> 3;                     // entry-sub 0..63
  for (int i = tid; i < GRID_N*8; i += 512) acc[i] = 0.f;
  __syncthreads();

  unsigned beg = colOff[c];
  unsigned end = (c < GRID_N-1) ? colOff[c+1] : (unsigned)NENT;
  const size_t qoff = (size_t)(h*8 + ql);

  unsigned base = beg;
  for (; base + 512 <= end; base += 512){
    unsigned e0 = base + es;
    uint4 r0 = entries[e0 +   0];
    uint4 r1 = entries[e0 +  64];
    uint4 r2 = entries[e0 + 128];
    uint4 r3 = entries[e0 + 192];
    uint4 r4 = entries[e0 + 256];
    uint4 r5 = entries[e0 + 320];
    uint4 r6 = entries[e0 + 384];
    uint4 r7 = entries[e0 + 448];
    float v0 = kdcf[((size_t)(r0.w >> 9) << 4) + qoff];
    float v1 = kdcf[((size_t)(r1.w >> 9) << 4) + qoff];
    float v2 = kdcf[((size_t)(r2.w >> 9) << 4) + qoff];
    float v3 = kdcf[((size_t)(r3.w >> 9) << 4) + qoff];
    float v4 = kdcf[((size_t)(r4.w >> 9) << 4) + qoff];
    float v5 = kdcf[((size_t)(r5.w >> 9) << 4) + qoff];
    float v6 = kdcf[((size_t)(r6.w >> 9) << 4) + qoff];
    float v7 = kdcf[((size_t)(r7.w >> 9) << 4) + qoff];
    scan_apply(r0, v0, ql, acc);
    scan_apply(r1, v1, ql, acc);
    scan_apply(r2, v2, ql, acc);
    scan_apply(r3, v3, ql, acc);
    scan_apply(r4, v4, ql, acc);
    scan_apply(r5, v5, ql, acc);
    scan_apply(r6, v6, ql, acc);
    scan_apply(r7, v7, ql, acc);
  }
  for (unsigned e = base + es; e < end; e += 64){
    uint4 rec = entries[e];
    float v = kdcf[((size_t)(rec.w >> 9) << 4) + qoff];
    scan_apply(rec, v, ql, acc);
  }
  __syncthreads();

  // disjoint writeback: this block owns float4 slots p = h*2+{0,1} of each cell
  for (int i = tid; i < GRID_N*2; i += 512){
    int y = i >> 1, pp = i & 1;
    float4 o;
    o.x = acc[y*8 + pp*4 + 0];
    o.y = acc[y*8 + pp*4 + 1];
    o.z = acc[y*8 + pp*4 + 2];
    o.w = acc[y*8 + pp*4 + 3];
    HTi4[((size_t)c*GRID_N + y)*4 + h*2 + pp] = o;
  }
}

// crop, apodize, conj(smaps) coil-combine; ACCUMULATES into out
__global__ void k_final(const cplx* __restrict__ Bg, const float* __restrict__ sr,
                        const float* __restrict__ si, const float* __restrict__ sc,
                        float* __restrict__ out, int pairs){
  int idx = blockIdx.x*blockDim.x + threadIdx.x;   // y*256+x
  if (idx >= IM_N*IM_N) return;
  int y = idx >> 8, x = idx & 255;
  float s2 = sc[y]*sc[x];
  float ax = 0.f, ay = 0.f;
  #pragma unroll
  for (int c = 0; c < NCOIL; ++c){
    cplx v = Bg[(size_t)c*PLANE + y*GRID_N + x];
    int gi = (c << 16) | idx;
    float rr = sr[gi], ii = si[gi];
    ax += rr*v.x + ii*v.y;      // conj(s)*v real
    ay += rr*v.y - ii*v.x;      // conj(s)*v imag
  }
  if (pairs){
    out[idx*2]   += ax * s2;
    out[idx*2+1] += ay * s2;
  } else {
    out[idx]     += ax * s2;
  }
}

// ---------------- fallback (round-2 validated fused atomic path) -------------
__global__ void k_gather_scatter_fb(const float* __restrict__ ktraj,
                                    const float* __restrict__ yre,
                                    const float* __restrict__ yim,
                                    const float* __restrict__ lraw,
                                    const cplx* __restrict__ KT,
                                    float* __restrict__ HT){
  int k = blockIdx.x*blockDim.x + threadIdx.x;
  if (k >= NK) return;
  float lam   = 1.0f/(1.0f + __expf(-lraw[0]));
  float omlam = 1.0f - lam;
  int iy[JW], ix[JW]; float wy[JW], wx[JW];
  {
    float tm = ktraj[k] * KSCALE;
    int base = (int)floorf(tm - 3.0f);
    #pragma unroll
    for (int j = 1; j <= JW; ++j){
      wy[j-1] = kb_w(tm - (float)(base+j));
      iy[j-1] = (base+j) & (GRID_N-1);
    }
  }
  {
    float tm = ktraj[NK + k] * KSCALE;
    int base = (int)floorf(tm - 3.0f);
    #pragma unroll
    for (int j = 1; j <= JW; ++j){
      wx[j-1] = kb_w(tm - (float)(base+j));
      ix[j-1] = (base+j) & (GRID_N-1);
    }
  }
  float accx[NCOIL], accy[NCOIL];
  #pragma unroll
  for (int c = 0; c < NCOIL; ++c){ accx[c]=0.f; accy[c]=0.f; }
  #pragma unroll
  for (int jx = 0; jx < JW; ++jx){
    int ox = ix[jx]*GRID_N;
    #pragma unroll
    for (int jy = 0; jy < JW; ++jy){
      float w2 = wx[jx]*wy[jy];
      size_t o = (size_t)(ox + iy[jy]);
      #pragma unroll
      for (int c = 0; c < NCOIL; ++c){
        cplx v = KT[(size_t)c*PLANE + o];
        accx[c] += w2*v.x; accy[c] += w2*v.y;
      }
    }
  }
  float kdx[NCOIL], kdy[NCOIL];
  #pragma unroll
  for (int c = 0; c < NCOIL; ++c){
    kdx[c] = lam*accx[c] + omlam*yre[(size_t)c*NK + k];
    kdy[c] = lam*accy[c] + omlam*yim[(size_t)c*NK + k];
  }
  #pragma unroll
  for (int jx = 0; jx < JW; ++jx){
    int ox = ix[jx]*GRID_N;
    #pragma unroll
    for (int jy = 0; jy < JW; ++jy){
      float w2 = wx[jx]*wy[jy];
      size_t o = (size_t)(ox + iy[jy]);
      #pragma unroll
      for (int c = 0; c < NCOIL; ++c){
        float* dst = HT + ((size_t)c*PLANE + o)*2;
        atomicAdd(dst,   w2*kdx[c]);
        atomicAdd(dst+1, w2*kdy[c]);
      }
    }
  }
}

extern "C" void kernel_launch(void* const* d_in, const int* in_sizes, int n_in,
                              void* d_out, int out_size, void* d_ws, size_t ws_size,
                              hipStream_t stream) {
  const float* ximg  = (const float*)d_in[0];
  const float* yre   = (const float*)d_in[1];
  const float* yim   = (const float*)d_in[2];
  const float* sre   = (const float*)d_in[3];
  const float* sim   = (const float*)d_in[4];
  const float* ktraj = (const float*)d_in[5];
  const float* lraw  = (const float*)d_in[6];
  float* out = (float*)d_out;

  char* ws = (char*)d_ws;
  const size_t REG = 16777216;                 // one planar grid: 512*512*8B*8
  int pairs = (out_size >= 2*IM_N*IM_N) ? 1 : 0;

  // primary layout (50.34 MB):
  //   [0, REG)      A planar; after fwd: kdc (8MB) + rank (0.5MB); later img planar
  //   [REG, 2REG)   B planar (KT); after c2i+fwd: fat entries (12.6MB); later img^T
  //   [2REG, 3REG)  KTi interleaved; reused as HTi by k_scan_col
  //   [3REG, ...)   sc (4KB), hist (2KB), colOff (2KB)
  const size_t need = 3*REG + 4096 + 2048 + 2048;

  if (ws_size >= need){
    cplx*     A     = (cplx*)ws;
    cplx*     Bb    = (cplx*)(ws + REG);
    float4*   KTi4  = (float4*)(ws + 2*REG);
    float*    sc    = (float*)(ws + 3*REG);
    unsigned* hist  = (unsigned*)(ws + 3*REG + 4096);
    unsigned* colOff= (unsigned*)(ws + 3*REG + 4096 + 2048);
    float4*   kdc4  = (float4*)ws;                         // overlays dead A
    unsigned* rank  = (unsigned*)(ws + (size_t)NK*16*4);   // +8,388,608
    uint4*    entries = (uint4*)(ws + REG);                // overlays dead Bb

    const int n4 = NCOIL*PLANE*2/4;

    k_sc_table<<<1,256,0,stream>>>(sc);
    k_zero4<<<(n4+255)/256,256,0,stream>>>((float4*)A, n4);
    k_fill<<<(NCOIL*IM_N*IM_N+255)/256,256,0,stream>>>(ximg, sre, sim, sc, A);

    // fwd fft2/512: rows over x, transpose, rows over y -> Bb = kg^T planar [x][y]
    k_fft_rows<-1><<<NCOIL*GRID_N,256,0,stream>>>(A, 1.0f);
    k_transpose<<<dim3(16,16,NCOIL),dim3(32,8),0,stream>>>(A, Bb);
    k_fft_rows<-1><<<NCOIL*GRID_N,256,0,stream>>>(Bb, 1.0f/(float)GRID_N);

    k_c2i<<<(PLANE*NCOIL+255)/256,256,0,stream>>>((const float2*)Bb, (float2*)KTi4);

    // forward interp + blend -> kdc over dead A (Bb planar now dead)
    k_fwd<<<(NK*4+255)/256,256,0,stream>>>(ktraj, yre, yim, lraw, KTi4, kdc4);

    // column binning (131K int atomics total)
    k_zero1<<<2,256,0,stream>>>((float*)hist, GRID_N);
    k_hist<<<NK/256,256,0,stream>>>(ktraj, hist, rank);
    k_scan512<<<1,GRID_N,0,stream>>>(hist, colOff);
    k_fill_entries<<<NK/256,256,0,stream>>>(ktraj, rank, hist, colOff, entries);

    // adjoint gridding: 512 columns x 2 q-halves, U=8 batched streaming,
    // 16KB LDS tiles, disjoint writeback over dead KTi
    k_scan_col<<<dim3(GRID_N,2),512,0,stream>>>(entries, colOff,
                                                (const float*)kdc4,
                                                KTi4);

    k_i2c<<<(PLANE*NCOIL+255)/256,256,0,stream>>>((const float2*)KTi4, (float2*)A);

    // adjoint ifft2*512: rows over y, transpose, rows over x -> Bb = img [y][x]
    k_fft_rows<+1><<<NCOIL*GRID_N,256,0,stream>>>(A, 1.0f);
    k_transpose<<<dim3(16,16,NCOIL),dim3(32,8),0,stream>>>(A, Bb);
    k_fft_rows<+1><<<NCOIL*GRID_N,256,0,stream>>>(Bb, 1.0f/(float)GRID_N);

    k_zero1<<<(out_size+255)/256,256,0,stream>>>(out, out_size);
    k_final<<<(IM_N*IM_N+255)/256,256,0,stream>>>(Bb, sre, sim, sc, out, pairs);
  } else {
    // fallback: round-2 validated path (needs 33.6 MB)
    float* sc = (float*)ws;
    cplx*  A  = (cplx*)(ws + 4096);
    cplx*  Bb = (cplx*)(ws + 4096 + REG);
    const int n4 = NCOIL*PLANE*2/4;

    k_sc_table<<<1,256,0,stream>>>(sc);
    k_zero4<<<(n4+255)/256,256,0,stream>>>((float4*)A, n4);
    k_fill<<<(NCOIL*IM_N*IM_N+255)/256,256,0,stream>>>(ximg, sre, sim, sc, A);
    k_fft_rows<-1><<<NCOIL*GRID_N,256,0,stream>>>(A, 1.0f);
    k_transpose<<<dim3(16,16,NCOIL),dim3(32,8),0,stream>>>(A, Bb);
    k_fft_rows<-1><<<NCOIL*GRID_N,256,0,stream>>>(Bb, 1.0f/(float)GRID_N);
    k_zero4<<<(n4+255)/256,256,0,stream>>>((float4*)A, n4);
    k_gather_scatter_fb<<<(NK+255)/256,256,0,stream>>>(ktraj, yre, yim, lraw, Bb, (float*)A);
    k_fft_rows<+1><<<NCOIL*GRID_N,256,0,stream>>>(A, 1.0f);
    k_transpose<<<dim3(16,16,NCOIL),dim3(32,8),0,stream>>>(A, Bb);
    k_fft_rows<+1><<<NCOIL*GRID_N,256,0,stream>>>(Bb, 1.0f/(float)GRID_N);
    k_zero1<<<(out_size+255)/256,256,0,stream>>>(out, out_size);
    k_final<<<(IM_N*IM_N+255)/256,256,0,stream>>>(Bb, sre, sim, sc, out, pairs);
  }
}

// Round 8
// 893.246 us; speedup vs baseline: 1.0798x; 1.0762x over previous
//
#include <hip/hip_runtime.h>
#include <math.h>

#define GRID_N 512
#define IM_N   256
#define NCOIL  8
#define NK     131072
#define PLANE  (GRID_N*GRID_N)
#define JW     6
#define NENT   (NK*JW)
#define BETA_F 13.8551003f   /* pi*sqrt((6/2)^2*(2-0.5)^2 - 0.8) */
#define KSCALE 81.48733086305042f  /* 512/(2*pi) */

struct cplx { float x, y; };

__device__ __forceinline__ float bessel_i0f(float x){
  // Abramowitz & Stegun 9.8.1 / 9.8.2, rel err < 2e-7
  if (x < 3.75f){
    float t = x*(1.0f/3.75f); t = t*t;
    return 1.0f + t*(3.5156229f + t*(3.0899424f + t*(1.2067492f
           + t*(0.2659732f + t*(0.0360768f + t*0.0045813f)))));
  } else {
    float t = 3.75f/x;
    float p = 0.39894228f + t*(0.01328592f + t*(0.00225319f + t*(-0.00157565f
            + t*(0.00916281f + t*(-0.02057706f + t*(0.02635537f
            + t*(-0.01647633f + t*0.00392377f)))))));
    return p * __expf(x) * rsqrtf(x);
  }
}

__device__ __forceinline__ float kb_w(float u){   // 1-axis KB weight, |u|<=3
  float uu = u*(1.0f/3.0f);
  float q = fmaxf(1.0f - uu*uu, 0.0f);
  return bessel_i0f(BETA_F*sqrtf(q)) * (1.0f/6.0f);
}

__device__ __forceinline__ unsigned bf16_of(float f){
  unsigned u = __float_as_uint(f);
  return (u + 0x8000u) >> 16;                 // round-to-nearest-ish
}

// Kaiser-Bessel apodization correction row table sc[256]
__global__ void k_sc_table(float* sc){
  int i = threadIdx.x;
  if (i >= IM_N) return;
  float n  = (i - IM_N*0.5f) * (1.0f/GRID_N);
  float pj = 3.14159265358979f * (float)JW * n;
  float t  = BETA_F*BETA_F - pj*pj;
  float sp = sqrtf(fmaxf(t, 1e-12f));
  float sn = sqrtf(fmaxf(-t, 1e-12f));
  float ft = (t > 0.0f) ? (sinhf(sp)/sp) : (sinf(sn)/sn);
  float sc0 = sinhf(BETA_F)/BETA_F;
  sc[i] = sc0/ft;
}

__global__ void k_zero4(float4* p, int n4){
  int i = blockIdx.x*blockDim.x + threadIdx.x;
  if (i < n4) p[i] = make_float4(0.f,0.f,0.f,0.f);
}

__global__ void k_zero1(float* p, int n){
  int i = blockIdx.x*blockDim.x + threadIdx.x;
  if (i < n) p[i] = 0.f;
}

// coil_images * sc2 into padded 512^2 planar grids (A zeroed beforehand)
__global__ void k_fill(const float* __restrict__ ximg, const float* __restrict__ sr,
                       const float* __restrict__ si, const float* __restrict__ sc,
                       cplx* __restrict__ A){
  int idx = blockIdx.x*blockDim.x + threadIdx.x;   // c*65536 + y*256 + x
  if (idx >= NCOIL*IM_N*IM_N) return;
  int c = idx >> 16;
  int pix = idx & 65535;
  int y = pix >> 8, x = pix & 255;
  float v = ximg[pix] * sc[y]*sc[x];
  cplx o; o.x = v * sr[idx]; o.y = v * si[idx];
  A[(size_t)c*PLANE + y*GRID_N + x] = o;
}

// in-place 512-pt radix-2 FFT on each contiguous row; DIR=-1 fwd, +1 inv(unnorm)
template<int DIR>
__global__ void k_fft_rows(cplx* __restrict__ buf, float scale){
  __shared__ cplx lds[GRID_N];
  cplx* p = buf + (size_t)blockIdx.x * GRID_N;
  int tid = threadIdx.x;                       // 256 threads
  for (int i = tid; i < GRID_N; i += 256){
    int r = __brev((unsigned)i) >> 23;         // 9-bit reverse
    lds[r] = p[i];
  }
  __syncthreads();
  for (int half = 1; half < GRID_N; half <<= 1){
    int j = tid & (half-1);
    int k = ((tid & ~(half-1)) << 1) | j;
    float ang = (float)DIR * 3.14159265358979f * (float)j / (float)half;
    float sw, cw; __sincosf(ang, &sw, &cw);
    cplx u = lds[k];
    cplx v = lds[k+half];
    cplx t; t.x = v.x*cw - v.y*sw; t.y = v.x*sw + v.y*cw;
    lds[k].x      = u.x + t.x; lds[k].y      = u.y + t.y;
    lds[k+half].x = u.x - t.x; lds[k+half].y = u.y - t.y;
    __syncthreads();
  }
  for (int i = tid; i < GRID_N; i += 256){
    cplx v = lds[i]; v.x *= scale; v.y *= scale; p[i] = v;
  }
}

// 512x512 tile transpose per coil plane, out[X][Y] = in[Y][X]
__global__ void k_transpose(const cplx* __restrict__ in, cplx* __restrict__ out){
  __shared__ cplx tile[32][33];
  int c  = blockIdx.z;
  int x0 = blockIdx.x*32, y0 = blockIdx.y*32;
  const cplx* ip = in  + (size_t)c*PLANE;
  cplx*       op = out + (size_t)c*PLANE;
  int tx = threadIdx.x, ty = threadIdx.y;      // (32,8)
  for (int dy = 0; dy < 32; dy += 8)
    tile[ty+dy][tx] = ip[(size_t)(y0+ty+dy)*GRID_N + (x0+tx)];
  __syncthreads();
  for (int dy = 0; dy < 32; dy += 8)
    op[(size_t)(x0+ty+dy)*GRID_N + (y0+tx)] = tile[tx][ty+dy];
}

// planar [c][cell] -> coil-interleaved [cell][8 float2]  (fully coalesced)
__global__ void k_c2i(const float2* __restrict__ plan, float2* __restrict__ inter){
  int t = blockIdx.x*blockDim.x + threadIdx.x;
  if (t >= PLANE*NCOIL) return;
  int c = t & 7; int cell = t >> 3;
  inter[(size_t)cell*8 + c] = plan[(size_t)c*PLANE + cell];
}

// coil-interleaved [cell][8 float2] -> planar [c][cell]
__global__ void k_i2c(const float2* __restrict__ inter, float2* __restrict__ plan){
  int t = blockIdx.x*blockDim.x + threadIdx.x;
  if (t >= PLANE*NCOIL) return;
  int c = t & 7; int cell = t >> 3;
  plan[(size_t)c*PLANE + cell] = inter[(size_t)cell*8 + c];
}

// forward interp + lambda blend: thread = (sample, coil-pair)
__global__ __launch_bounds__(256) void k_fwd(
    const float* __restrict__ ktraj, const float* __restrict__ yre,
    const float* __restrict__ yim, const float* __restrict__ lraw,
    const float4* __restrict__ KTi4, float4* __restrict__ kdc4){
  int t = blockIdx.x*blockDim.x + threadIdx.x;
  if (t >= NK*4) return;
  int k = t >> 2, p = t & 3;

  int iy[JW], ix[JW]; float wy[JW], wx[JW];
  {
    float tm = ktraj[k] * KSCALE;
    int base = (int)floorf(tm - 3.0f);
    #pragma unroll
    for (int j = 1; j <= JW; ++j){
      int fidx = base + j;
      wy[j-1] = kb_w(tm - (float)fidx);
      iy[j-1] = fidx & (GRID_N-1);
    }
  }
  {
    float tm = ktraj[NK + k] * KSCALE;
    int base = (int)floorf(tm - 3.0f);
    #pragma unroll
    for (int j = 1; j <= JW; ++j){
      int fidx = base + j;
      wx[j-1] = kb_w(tm - (float)fidx);
      ix[j-1] = fidx & (GRID_N-1);
    }
  }

  float ax=0.f, ay=0.f, az=0.f, aw=0.f;
  #pragma unroll
  for (int jx = 0; jx < JW; ++jx){
    int ox = ix[jx]*GRID_N;
    #pragma unroll
    for (int jy = 0; jy < JW; ++jy){
      float w2 = wx[jx]*wy[jy];
      float4 v = KTi4[(size_t)(ox + iy[jy])*4 + p];
      ax += w2*v.x; ay += w2*v.y; az += w2*v.z; aw += w2*v.w;
    }
  }
  float lam = 1.0f/(1.0f + __expf(-lraw[0]));
  float oml = 1.0f - lam;
  int c0 = 2*p;
  float4 o;
  o.x = lam*ax + oml*yre[(size_t)c0*NK + k];
  o.y = lam*ay + oml*yim[(size_t)c0*NK + k];
  o.z = lam*az + oml*yre[(size_t)(c0+1)*NK + k];
  o.w = lam*aw + oml*yim[(size_t)(c0+1)*NK + k];
  kdc4[(size_t)k*4 + p] = o;
}

// histogram over x-base bins + per-sample rank
__global__ void k_hist(const float* __restrict__ ktraj, unsigned* __restrict__ hist,
                       unsigned* __restrict__ rank){
  int k = blockIdx.x*blockDim.x + threadIdx.x;
  if (k >= NK) return;
  float tmx = ktraj[NK + k] * KSCALE;
  int bx = (int)floorf(tmx - 3.0f);
  rank[k] = atomicAdd(&hist[bx & (GRID_N-1)], 1u);
}

// column counts + exclusive scan (single block of 512)
__global__ void k_scan512(const unsigned* __restrict__ hist, unsigned* __restrict__ colOff){
  __shared__ unsigned s[GRID_N];
  int t = threadIdx.x;
  unsigned v = 0;
  #pragma unroll
  for (int d = 1; d <= JW; ++d) v += hist[(t - d) & (GRID_N-1)];
  s[t] = v;
  __syncthreads();
  for (int off = 1; off < GRID_N; off <<= 1){
    unsigned add = (t >= off) ? s[t - off] : 0u;
    __syncthreads();
    s[t] += add;
    __syncthreads();
  }
  colOff[t] = (t == 0) ? 0u : s[t-1];
}

// place fully-expanded 16B records at closed-form positions (no contention):
// rec = { bf16(wx*wy0)|bf16(wx*wy1)<<16, bf16(wx*wy2)|bf16(wx*wy3)<<16,
//         bf16(wx*wy4)|bf16(wx*wy5)<<16, (kk<<9)|(by&511) }
__global__ void k_fill_entries(const float* __restrict__ ktraj,
                               const unsigned* __restrict__ rank,
                               const unsigned* __restrict__ hist,
                               const unsigned* __restrict__ colOff,
                               uint4* __restrict__ entries){
  int k = blockIdx.x*blockDim.x + threadIdx.x;
  if (k >= NK) return;
  float tmy = ktraj[k] * KSCALE;
  int by = (int)floorf(tmy - 3.0f);
  float wy[JW];
  #pragma unroll
  for (int j = 1; j <= JW; ++j) wy[j-1] = kb_w(tmy - (float)(by + j));

  float tmx = ktraj[NK + k] * KSCALE;
  int bx = (int)floorf(tmx - 3.0f);
  unsigned r = rank[k];
  unsigned tag = ((unsigned)k << 9) | ((unsigned)(by & (GRID_N-1)));
  unsigned run = 0;
  #pragma unroll
  for (int j = 1; j <= JW; ++j){
    int cc = (bx + j) & (GRID_N-1);
    float wx = kb_w(tmx - (float)(bx + j));
    uint4 rec;
    rec.x = bf16_of(wx*wy[0]) | (bf16_of(wx*wy[1]) << 16);
    rec.y = bf16_of(wx*wy[2]) | (bf16_of(wx*wy[3]) << 16);
    rec.z = bf16_of(wx*wy[4]) | (bf16_of(wx*wy[5]) << 16);
    rec.w = tag;
    entries[colOff[cc] + run + r] = rec;
    run += hist[cc];
  }
}

// one entry's contribution for one coil-float q: 6 LDS atomics
__device__ __forceinline__ void scan_apply(uint4 rec, float v, int ql, float* acc){
  int by = (int)(rec.w & (GRID_N-1));
  float w0 = __uint_as_float(rec.x << 16);
  float w1 = __uint_as_float(rec.x & 0xFFFF0000u);
  float w2 = __uint_as_float(rec.y << 16);
  float w3 = __uint_as_float(rec.y & 0xFFFF0000u);
  float w4 = __uint_as_float(rec.z << 16);
  float w5 = __uint_as_float(rec.z & 0xFFFF0000u);
  int y;
  y = (by+1)&(GRID_N-1); atomicAdd(&acc[y*8+ql], w0*v);
  y = (by+2)&(GRID_N-1); atomicAdd(&acc[y*8+ql], w1*v);
  y = (by+3)&(GRID_N-1); atomicAdd(&acc[y*8+ql], w2*v);
  y = (by+4)&(GRID_N-1); atomicAdd(&acc[y*8+ql], w3*v);
  y = (by+5)&(GRID_N-1); atomicAdd(&acc[y*8+ql], w4*v);
  y = (by+6)&(GRID_N-1); atomicAdd(&acc[y*8+ql], w5*v);
}

// adjoint gridding scan: block = (x-column, q-half), 512 threads (8 waves).
// Lane = (entry-sub es 0..63, q-sub ql 0..7). 2-stage software pipeline:
// prefetch next batch's 8 records (named regs) while current batch's kdc
// gathers + 48 ds_adds retire. __launch_bounds__(512,2) lifts the VGPR cap
// to 256 so the 16 in-flight loads actually stay live (r7: 40 VGPR killed MLP).
__global__ __launch_bounds__(512, 2) void k_scan_col(
    const uint4* __restrict__ entries, const unsigned* __restrict__ colOff,
    const float* __restrict__ kdcf,     // [k][16] floats
    float4* __restrict__ HTi4){         // [cell][4 float4]
  __shared__ float acc[GRID_N*8];
  const int c = blockIdx.x, h = blockIdx.y;    // column, q-half
  const int tid = threadIdx.x;
  const int ql = tid & 7;                      // q within half
  const int es = tid >> 3;                     // entry-sub 0..63
  for (int i = tid; i < GRID_N*8; i += 512) acc[i] = 0.f;
  __syncthreads();

  unsigned beg = colOff[c];
  unsigned end = (c < GRID_N-1) ? colOff[c+1] : (unsigned)NENT;
  const size_t qoff = (size_t)(h*8 + ql);
  const unsigned nb = (end - beg) >> 9;        // full 512-entry batches

  unsigned base = beg + es;
  uint4 r0,r1,r2,r3,r4,r5,r6,r7;
  if (nb > 0){
    r0 = entries[base +   0];
    r1 = entries[base +  64];
    r2 = entries[base + 128];
    r3 = entries[base + 192];
    r4 = entries[base + 256];
    r5 = entries[base + 320];
    r6 = entries[base + 384];
    r7 = entries[base + 448];
  }
  for (unsigned b = 0; b < nb; ++b){
    // kdc gathers for current batch (8 independent chains)
    float v0 = kdcf[((size_t)(r0.w >> 9) << 4) + qoff];
    float v1 = kdcf[((size_t)(r1.w >> 9) << 4) + qoff];
    float v2 = kdcf[((size_t)(r2.w >> 9) << 4) + qoff];
    float v3 = kdcf[((size_t)(r3.w >> 9) << 4) + qoff];
    float v4 = kdcf[((size_t)(r4.w >> 9) << 4) + qoff];
    float v5 = kdcf[((size_t)(r5.w >> 9) << 4) + qoff];
    float v6 = kdcf[((size_t)(r6.w >> 9) << 4) + qoff];
    float v7 = kdcf[((size_t)(r7.w >> 9) << 4) + qoff];
    // prefetch next batch's records while v's are in flight
    unsigned nbase = base + 512;
    uint4 n0,n1,n2,n3,n4,n5,n6,n7;
    if (b + 1 < nb){
      n0 = entries[nbase +   0];
      n1 = entries[nbase +  64];
      n2 = entries[nbase + 128];
      n3 = entries[nbase + 192];
      n4 = entries[nbase + 256];
      n5 = entries[nbase + 320];
      n6 = entries[nbase + 384];
      n7 = entries[nbase + 448];
    } else {
      n0 = r0; n1 = r1; n2 = r2; n3 = r3; n4 = r4; n5 = r5; n6 = r6; n7 = r7;
    }
    scan_apply(r0, v0, ql, acc);
    scan_apply(r1, v1, ql, acc);
    scan_apply(r2, v2, ql, acc);
    scan_apply(r3, v3, ql, acc);
    scan_apply(r4, v4, ql, acc);
    scan_apply(r5, v5, ql, acc);
    scan_apply(r6, v6, ql, acc);
    scan_apply(r7, v7, ql, acc);
    r0 = n0; r1 = n1; r2 = n2; r3 = n3; r4 = n4; r5 = n5; r6 = n6; r7 = n7;
    base = nbase;
  }
  // remainder (< 512 entries)
  for (unsigned e = beg + (nb << 9) + es; e < end; e += 64){
    uint4 rec = entries[e];
    float v = kdcf[((size_t)(rec.w >> 9) << 4) + qoff];
    scan_apply(rec, v, ql, acc);
  }
  __syncthreads();

  // disjoint writeback: this block owns float4 slots p = h*2+{0,1} of each cell
  for (int i = tid; i < GRID_N*2; i += 512){
    int y = i >> 1, pp = i & 1;
    float4 o;
    o.x = acc[y*8 + pp*4 + 0];
    o.y = acc[y*8 + pp*4 + 1];
    o.z = acc[y*8 + pp*4 + 2];
    o.w = acc[y*8 + pp*4 + 3];
    HTi4[((size_t)c*GRID_N + y)*4 + h*2 + pp] = o;
  }
}

// crop, apodize, conj(smaps) coil-combine; ACCUMULATES into out
__global__ void k_final(const cplx* __restrict__ Bg, const float* __restrict__ sr,
                        const float* __restrict__ si, const float* __restrict__ sc,
                        float* __restrict__ out, int pairs){
  int idx = blockIdx.x*blockDim.x + threadIdx.x;   // y*256+x
  if (idx >= IM_N*IM_N) return;
  int y = idx >> 8, x = idx & 255;
  float s2 = sc[y]*sc[x];
  float ax = 0.f, ay = 0.f;
  #pragma unroll
  for (int c = 0; c < NCOIL; ++c){
    cplx v = Bg[(size_t)c*PLANE + y*GRID_N + x];
    int gi = (c << 16) | idx;
    float rr = sr[gi], ii = si[gi];
    ax += rr*v.x + ii*v.y;      // conj(s)*v real
    ay += rr*v.y - ii*v.x;      // conj(s)*v imag
  }
  if (pairs){
    out[idx*2]   += ax * s2;
    out[idx*2+1] += ay * s2;
  } else {
    out[idx]     += ax * s2;
  }
}

// ---------------- fallback (round-2 validated fused atomic path) -------------
__global__ void k_gather_scatter_fb(const float* __restrict__ ktraj,
                                    const float* __restrict__ yre,
                                    const float* __restrict__ yim,
                                    const float* __restrict__ lraw,
                                    const cplx* __restrict__ KT,
                                    float* __restrict__ HT){
  int k = blockIdx.x*blockDim.x + threadIdx.x;
  if (k >= NK) return;
  float lam   = 1.0f/(1.0f + __expf(-lraw[0]));
  float omlam = 1.0f - lam;
  int iy[JW], ix[JW]; float wy[JW], wx[JW];
  {
    float tm = ktraj[k] * KSCALE;
    int base = (int)floorf(tm - 3.0f);
    #pragma unroll
    for (int j = 1; j <= JW; ++j){
      wy[j-1] = kb_w(tm - (float)(base+j));
      iy[j-1] = (base+j) & (GRID_N-1);
    }
  }
  {
    float tm = ktraj[NK + k] * KSCALE;
    int base = (int)floorf(tm - 3.0f);
    #pragma unroll
    for (int j = 1; j <= JW; ++j){
      wx[j-1] = kb_w(tm - (float)(base+j));
      ix[j-1] = (base+j) & (GRID_N-1);
    }
  }
  float accx[NCOIL], accy[NCOIL];
  #pragma unroll
  for (int c = 0; c < NCOIL; ++c){ accx[c]=0.f; accy[c]=0.f; }
  #pragma unroll
  for (int jx = 0; jx < JW; ++jx){
    int ox = ix[jx]*GRID_N;
    #pragma unroll
    for (int jy = 0; jy < JW; ++jy){
      float w2 = wx[jx]*wy[jy];
      size_t o = (size_t)(ox + iy[jy]);
      #pragma unroll
      for (int c = 0; c < NCOIL; ++c){
        cplx v = KT[(size_t)c*PLANE + o];
        accx[c] += w2*v.x; accy[c] += w2*v.y;
      }
    }
  }
  float kdx[NCOIL], kdy[NCOIL];
  #pragma unroll
  for (int c = 0; c < NCOIL; ++c){
    kdx[c] = lam*accx[c] + omlam*yre[(size_t)c*NK + k];
    kdy[c] = lam*accy[c] + omlam*yim[(size_t)c*NK + k];
  }
  #pragma unroll
  for (int jx = 0; jx < JW; ++jx){
    int ox = ix[jx]*GRID_N;
    #pragma unroll
    for (int jy = 0; jy < JW; ++jy){
      float w2 = wx[jx]*wy[jy];
      size_t o = (size_t)(ox + iy[jy]);
      #pragma unroll
      for (int c = 0; c < NCOIL; ++c){
        float* dst = HT + ((size_t)c*PLANE + o)*2;
        atomicAdd(dst,   w2*kdx[c]);
        atomicAdd(dst+1, w2*kdy[c]);
      }
    }
  }
}

extern "C" void kernel_launch(void* const* d_in, const int* in_sizes, int n_in,
                              void* d_out, int out_size, void* d_ws, size_t ws_size,
                              hipStream_t stream) {
  const float* ximg  = (const float*)d_in[0];
  const float* yre   = (const float*)d_in[1];
  const float* yim   = (const float*)d_in[2];
  const float* sre   = (const float*)d_in[3];
  const float* sim   = (const float*)d_in[4];
  const float* ktraj = (const float*)d_in[5];
  const float* lraw  = (const float*)d_in[6];
  float* out = (float*)d_out;

  char* ws = (char*)d_ws;
  const size_t REG = 16777216;                 // one planar grid: 512*512*8B*8
  int pairs = (out_size >= 2*IM_N*IM_N) ? 1 : 0;

  // primary layout (50.34 MB):
  //   [0, REG)      A planar; after fwd: kdc (8MB) + rank (0.5MB); later img planar
  //   [REG, 2REG)   B planar (KT); after c2i+fwd: fat entries (12.6MB); later img^T
  //   [2REG, 3REG)  KTi interleaved; reused as HTi by k_scan_col
  //   [3REG, ...)   sc (4KB), hist (2KB), colOff (2KB)
  const size_t need = 3*REG + 4096 + 2048 + 2048;

  if (ws_size >= need){
    cplx*     A     = (cplx*)ws;
    cplx*     Bb    = (cplx*)(ws + REG);
    float4*   KTi4  = (float4*)(ws + 2*REG);
    float*    sc    = (float*)(ws + 3*REG);
    unsigned* hist  = (unsigned*)(ws + 3*REG + 4096);
    unsigned* colOff= (unsigned*)(ws + 3*REG + 4096 + 2048);
    float4*   kdc4  = (float4*)ws;                         // overlays dead A
    unsigned* rank  = (unsigned*)(ws + (size_t)NK*16*4);   // +8,388,608
    uint4*    entries = (uint4*)(ws + REG);                // overlays dead Bb

    const int n4 = NCOIL*PLANE*2/4;

    k_sc_table<<<1,256,0,stream>>>(sc);
    k_zero4<<<(n4+255)/256,256,0,stream>>>((float4*)A, n4);
    k_fill<<<(NCOIL*IM_N*IM_N+255)/256,256,0,stream>>>(ximg, sre, sim, sc, A);

    // fwd fft2/512: rows over x, transpose, rows over y -> Bb = kg^T planar [x][y]
    k_fft_rows<-1><<<NCOIL*GRID_N,256,0,stream>>>(A, 1.0f);
    k_transpose<<<dim3(16,16,NCOIL),dim3(32,8),0,stream>>>(A, Bb);
    k_fft_rows<-1><<<NCOIL*GRID_N,256,0,stream>>>(Bb, 1.0f/(float)GRID_N);

    k_c2i<<<(PLANE*NCOIL+255)/256,256,0,stream>>>((const float2*)Bb, (float2*)KTi4);

    // forward interp + blend -> kdc over dead A (Bb planar now dead)
    k_fwd<<<(NK*4+255)/256,256,0,stream>>>(ktraj, yre, yim, lraw, KTi4, kdc4);

    // column binning (131K int atomics total)
    k_zero1<<<2,256,0,stream>>>((float*)hist, GRID_N);
    k_hist<<<NK/256,256,0,stream>>>(ktraj, hist, rank);
    k_scan512<<<1,GRID_N,0,stream>>>(hist, colOff);
    k_fill_entries<<<NK/256,256,0,stream>>>(ktraj, rank, hist, colOff, entries);

    // adjoint gridding: 512 columns x 2 q-halves, pipelined batched streaming,
    // 16KB LDS tiles, disjoint writeback over dead KTi
    k_scan_col<<<dim3(GRID_N,2),512,0,stream>>>(entries, colOff,
                                                (const float*)kdc4,
                                                KTi4);

    k_i2c<<<(PLANE*NCOIL+255)/256,256,0,stream>>>((const float2*)KTi4, (float2*)A);

    // adjoint ifft2*512: rows over y, transpose, rows over x -> Bb = img [y][x]
    k_fft_rows<+1><<<NCOIL*GRID_N,256,0,stream>>>(A, 1.0f);
    k_transpose<<<dim3(16,16,NCOIL),dim3(32,8),0,stream>>>(A, Bb);
    k_fft_rows<+1><<<NCOIL*GRID_N,256,0,stream>>>(Bb, 1.0f/(float)GRID_N);

    k_zero1<<<(out_size+255)/256,256,0,stream>>>(out, out_size);
    k_final<<<(IM_N*IM_N+255)/256,256,0,stream>>>(Bb, sre, sim, sc, out, pairs);
  } else {
    // fallback: round-2 validated path (needs 33.6 MB)
    float* sc = (float*)ws;
    cplx*  A  = (cplx*)(ws + 4096);
    cplx*  Bb = (cplx*)(ws + 4096 + REG);
    const int n4 = NCOIL*PLANE*2/4;

    k_sc_table<<<1,256,0,stream>>>(sc);
    k_zero4<<<(n4+255)/256,256,0,stream>>>((float4*)A, n4);
    k_fill<<<(NCOIL*IM_N*IM_N+255)/256,256,0,stream>>>(ximg, sre, sim, sc, A);
    k_fft_rows<-1><<<NCOIL*GRID_N,256,0,stream>>>(A, 1.0f);
    k_transpose<<<dim3(16,16,NCOIL),dim3(32,8),0,stream>>>(A, Bb);
    k_fft_rows<-1><<<NCOIL*GRID_N,256,0,stream>>>(Bb, 1.0f/(float)GRID_N);
    k_zero4<<<(n4+255)/256,256,0,stream>>>((float4*)A, n4);
    k_gather_scatter_fb<<<(NK+255)/256,256,0,stream>>>(ktraj, yre, yim, lraw, Bb, (float*)A);
    k_fft_rows<+1><<<NCOIL*GRID_N,256,0,stream>>>(A, 1.0f);
    k_transpose<<<dim3(16,16,NCOIL),dim3(32,8),0,stream>>>(A, Bb);
    k_fft_rows<+1><<<NCOIL*GRID_N,256,0,stream>>>(Bb, 1.0f/(float)GRID_N);
    k_zero1<<<(out_size+255)/256,256,0,stream>>>(out, out_size);
    k_final<<<(IM_N*IM_N+255)/256,256,0,stream>>>(Bb, sre, sim, sc, out, pairs);
  }
}